// Round 1
// baseline (2020.091 us; speedup 1.0000x reference)
//
#include <hip/hip_runtime.h>
#include <hip/hip_bf16.h>
#include <cstdint>

// ============================================================================
// Hybrid e2e STN pipeline, fp32 correctness-first baseline.
// Stages: rasterize -> pool -> stn mlp -> affine+grid_sample (img+mask)
//         -> im2col -> conv GEMM(relu) -> pe GEMM(+pos) -> LN1 -> qkv GEMM
//         -> attention -> proj GEMM(resid) -> LN2 -> mlp1 GEMM(gelu)
//         -> mlp2 GEMM(resid) -> roi head (+fc softmax)
// ============================================================================

#define B_    16
#define HH    512
#define WW    512
#define NF_   1024
#define EMB_  768
#define HEADS_ 12
#define GG    16
#define NTOK  256            // G*G
#define M_    (B_*NTOK)      // 4096 rows in all token GEMMs
#define KCONV 3072           // 3*32*32

// ---------------------------------------------------------------------------
// rasterize: diagonal segments into seg mask (B,512,512), mask pre-zeroed
// ---------------------------------------------------------------------------
__global__ __launch_bounds__(128)
void raster_kernel(const float* __restrict__ lm, float* __restrict__ seg) {
    int b = blockIdx.x;
    int s = threadIdx.x;
    if (s >= 117) return;
    int seg0 = (s < 43) ? s : ((s < 92) ? s + 1 : s + 2);
    const float* p = lm + (size_t)b * 240;
    int p1x = min(max((int)(p[seg0*2 + 0] * 512.0f), 0), 511);
    int p1y = min(max((int)(p[seg0*2 + 1] * 512.0f), 0), 511);
    int p2x = min(max((int)(p[(seg0+1)*2 + 0] * 512.0f), 0), 511);
    int p2y = min(max((int)(p[(seg0+1)*2 + 1] * 512.0f), 0), 511);
    int dy = p2y - p1y, dx = p2x - p1x;
    int kmax = min(dy, dx);      // valid iff k < dy && k < dx
    float* sb = seg + (size_t)b * (HH*WW);
    for (int k = 0; k < kmax; ++k) {
        int yi = min(p1y + k, 511);
        int xi = min(p1x + k, 511);
        sb[yi*WW + xi] = 1.0f;
    }
}

// ---------------------------------------------------------------------------
// pooled[b,oy,ox] = mean of 16x16 block of seg
// ---------------------------------------------------------------------------
__global__ __launch_bounds__(256)
void pool_kernel(const float* __restrict__ seg, float* __restrict__ pooled) {
    int idx = blockIdx.x * 256 + threadIdx.x;     // 16*32*32 = 16384
    int ox = idx & 31, oy = (idx >> 5) & 31, b = idx >> 10;
    const float* sb = seg + (size_t)b * (HH*WW) + (oy*16)*WW + ox*16;
    float s = 0.0f;
    for (int dy = 0; dy < 16; ++dy) {
        #pragma unroll
        for (int dx = 0; dx < 16; ++dx) s += sb[dy*WW + dx];
    }
    pooled[idx] = s * (1.0f/256.0f);
}

// ---------------------------------------------------------------------------
// stn: h = tanh(pooled@w1+b1) (50); theta = h@w2+b2 (6)
// ---------------------------------------------------------------------------
__global__ __launch_bounds__(64)
void stn_kernel(const float* __restrict__ pooled,
                const float* __restrict__ w1, const float* __restrict__ b1,
                const float* __restrict__ w2, const float* __restrict__ b2,
                float* __restrict__ theta) {
    __shared__ float pl[1024];
    __shared__ float hl[50];
    int b = blockIdx.x, tid = threadIdx.x;
    for (int i = tid; i < 1024; i += 64) pl[i] = pooled[b*1024 + i];
    __syncthreads();
    if (tid < 50) {
        float acc = b1[tid];
        for (int k = 0; k < 1024; ++k) acc += pl[k] * w1[k*50 + tid];
        hl[tid] = tanhf(acc);
    }
    __syncthreads();
    if (tid < 6) {
        float acc = b2[tid];
        for (int k = 0; k < 50; ++k) acc += hl[k] * w2[k*6 + tid];
        theta[b*6 + tid] = acc;
    }
}

// ---------------------------------------------------------------------------
// fused affine_grid + grid_sample for img (3ch) and mask (1ch)
// ---------------------------------------------------------------------------
__global__ __launch_bounds__(256)
void gridsample_kernel(const float* __restrict__ x, const float* __restrict__ seg,
                       const float* __restrict__ theta,
                       float* __restrict__ timg, float* __restrict__ tmask) {
    size_t idx = (size_t)blockIdx.x * 256 + threadIdx.x;   // B*H*W
    int xx = (int)(idx & 511);
    int yy = (int)((idx >> 9) & 511);
    int b  = (int)(idx >> 18);
    __shared__ float th[6];
    if (threadIdx.x < 6) th[threadIdx.x] = theta[b*6 + threadIdx.x];
    __syncthreads();
    float gx = (2.0f*xx + 1.0f) * (1.0f/512.0f) - 1.0f;
    float gy = (2.0f*yy + 1.0f) * (1.0f/512.0f) - 1.0f;
    float g0 = gx*th[0] + gy*th[1] + th[2];
    float g1 = gx*th[3] + gy*th[4] + th[5];
    float fx = ((g0 + 1.0f)*512.0f - 1.0f)*0.5f;
    float fy = ((g1 + 1.0f)*512.0f - 1.0f)*0.5f;
    float x0f = floorf(fx), y0f = floorf(fy);
    float wx1 = fx - x0f,  wy1 = fy - y0f;
    int ix0 = (int)x0f, iy0 = (int)y0f;
    int ix1 = ix0 + 1,  iy1 = iy0 + 1;
    float fy0ok = (iy0 >= 0 && iy0 < HH) ? 1.0f : 0.0f;
    float fy1ok = (iy1 >= 0 && iy1 < HH) ? 1.0f : 0.0f;
    float fx0ok = (ix0 >= 0 && ix0 < WW) ? 1.0f : 0.0f;
    float fx1ok = (ix1 >= 0 && ix1 < WW) ? 1.0f : 0.0f;
    float w00 = (1.0f-wy1)*(1.0f-wx1) * fy0ok * fx0ok;
    float w01 = (1.0f-wy1)*wx1        * fy0ok * fx1ok;
    float w10 = wy1*(1.0f-wx1)        * fy1ok * fx0ok;
    float w11 = wy1*wx1               * fy1ok * fx1ok;
    int cx0 = min(max(ix0,0),511), cx1 = min(max(ix1,0),511);
    int cy0 = min(max(iy0,0),511), cy1 = min(max(iy1,0),511);
    int i00 = cy0*WW + cx0, i01 = cy0*WW + cx1, i10 = cy1*WW + cx0, i11 = cy1*WW + cx1;
    size_t pix = (size_t)yy*WW + xx;
    #pragma unroll
    for (int c = 0; c < 3; ++c) {
        const float* pl = x + ((size_t)(b*3 + c)) * (HH*WW);
        float v = w00*pl[i00] + w01*pl[i01] + w10*pl[i10] + w11*pl[i11];
        timg[((size_t)(b*3 + c))*(HH*WW) + pix] = v;
    }
    const float* sp = seg + (size_t)b * (HH*WW);
    float mv = w00*sp[i00] + w01*sp[i01] + w10*sp[i10] + w11*sp[i11];
    tmask[(size_t)b*(HH*WW) + pix] = mv;
}

// ---------------------------------------------------------------------------
// im2col: A[m,k], m=b*256+py*16+px, k=c*1024+ky*32+kx
// ---------------------------------------------------------------------------
__global__ __launch_bounds__(256)
void im2col_kernel(const float* __restrict__ timg, float* __restrict__ A) {
    int idx = blockIdx.x * 256 + threadIdx.x;     // 4096*3072
    int k = idx % KCONV;
    int m = idx / KCONV;
    int kx = k & 31, ky = (k >> 5) & 31, c = k >> 10;
    int px = m & 15, py = (m >> 4) & 15, b = m >> 8;
    A[idx] = timg[((size_t)(b*3 + c)*HH + py*32 + ky)*WW + px*32 + kx];
}

// ---------------------------------------------------------------------------
// generic fp32 GEMM: C = A(MxK) * B(KxN) + bias, epilogue variants.
// TRANSB: B given as (N,K) row-major (e.g. conv_w).
// M,N mult of 64; K mult of 32. 256 thr, 64x64 tile, 4x4 micro.
// ---------------------------------------------------------------------------
enum { EPI_NONE=0, EPI_RELU=1, EPI_POS=2, EPI_RESID=3, EPI_GELU=4 };

template<int EPI, bool TRANSB>
__global__ __launch_bounds__(256)
void gemm_kernel(const float* __restrict__ A, const float* __restrict__ B,
                 const float* __restrict__ bias, const float* __restrict__ extra,
                 float* __restrict__ C, int M, int N, int K) {
    constexpr int BSTR = TRANSB ? 68 : 64;
    __shared__ __align__(16) float As[32][68];
    __shared__ __align__(16) float Bs[32][BSTR];
    const int tid = threadIdx.x;
    const int bm = blockIdx.y * 64;
    const int bn = blockIdx.x * 64;
    const int tx = tid & 15, ty = tid >> 4;
    float acc[4][4] = {};
    for (int k0 = 0; k0 < K; k0 += 32) {
        #pragma unroll
        for (int l = 0; l < 2; ++l) {
            int idx = tid + l*256;
            int r = idx >> 3, c = idx & 7;
            float4 v = *reinterpret_cast<const float4*>(A + (size_t)(bm + r)*K + k0 + c*4);
            As[c*4+0][r] = v.x; As[c*4+1][r] = v.y; As[c*4+2][r] = v.z; As[c*4+3][r] = v.w;
        }
        if (TRANSB) {
            #pragma unroll
            for (int l = 0; l < 2; ++l) {
                int idx = tid + l*256;
                int r = idx >> 3, c = idx & 7;   // r: n-local, c: k-float4
                float4 v = *reinterpret_cast<const float4*>(B + (size_t)(bn + r)*K + k0 + c*4);
                Bs[c*4+0][r] = v.x; Bs[c*4+1][r] = v.y; Bs[c*4+2][r] = v.z; Bs[c*4+3][r] = v.w;
            }
        } else {
            #pragma unroll
            for (int l = 0; l < 2; ++l) {
                int idx = tid + l*256;
                int r = idx >> 4, c = idx & 15;
                *reinterpret_cast<float4*>(&Bs[r][c*4]) =
                    *reinterpret_cast<const float4*>(B + (size_t)(k0 + r)*N + bn + c*4);
            }
        }
        __syncthreads();
        #pragma unroll
        for (int kk = 0; kk < 32; ++kk) {
            float4 av = *reinterpret_cast<const float4*>(&As[kk][ty*4]);
            float4 bv = *reinterpret_cast<const float4*>(&Bs[kk][tx*4]);
            float a[4] = {av.x, av.y, av.z, av.w};
            float bb[4] = {bv.x, bv.y, bv.z, bv.w};
            #pragma unroll
            for (int i = 0; i < 4; ++i)
                #pragma unroll
                for (int j = 0; j < 4; ++j)
                    acc[i][j] += a[i]*bb[j];
        }
        __syncthreads();
    }
    #pragma unroll
    for (int i = 0; i < 4; ++i) {
        int m = bm + ty*4 + i;
        size_t ro = (size_t)m * N;
        #pragma unroll
        for (int j = 0; j < 4; ++j) {
            int n = bn + tx*4 + j;
            float v = acc[i][j] + bias[n];
            if (EPI == EPI_POS)   v += extra[(size_t)(m & 255)*N + n];
            if (EPI == EPI_RELU)  v = fmaxf(v, 0.0f);
            if (EPI == EPI_GELU) {
                float u = v;
                v = 0.5f*u*(1.0f + tanhf(0.7978845608028654f*(u + 0.044715f*u*u*u)));
            }
            if (EPI == EPI_RESID) v += C[ro + n];
            C[ro + n] = v;
        }
    }
}

// ---------------------------------------------------------------------------
// layernorm over rows of 768
// ---------------------------------------------------------------------------
__global__ __launch_bounds__(256)
void ln_kernel(const float* __restrict__ x, const float* __restrict__ g,
               const float* __restrict__ be, float* __restrict__ out) {
    int r = blockIdx.x, tid = threadIdx.x;
    const float* xr = x + (size_t)r * EMB_;
    float v0 = xr[tid], v1 = xr[tid+256], v2 = xr[tid+512];
    float s = v0+v1+v2, s2 = v0*v0 + v1*v1 + v2*v2;
    __shared__ float red[8];
    #pragma unroll
    for (int off = 32; off; off >>= 1) { s += __shfl_xor(s, off); s2 += __shfl_xor(s2, off); }
    if ((tid & 63) == 0) { red[tid>>6] = s; red[4 + (tid>>6)] = s2; }
    __syncthreads();
    s  = red[0]+red[1]+red[2]+red[3];
    s2 = red[4]+red[5]+red[6]+red[7];
    float mean = s * (1.0f/768.0f);
    float var  = s2 * (1.0f/768.0f) - mean*mean;
    float rstd = rsqrtf(var + 1e-5f);
    float* orow = out + (size_t)r * EMB_;
    orow[tid]     = (v0-mean)*rstd*g[tid]     + be[tid];
    orow[tid+256] = (v1-mean)*rstd*g[tid+256] + be[tid+256];
    orow[tid+512] = (v2-mean)*rstd*g[tid+512] + be[tid+512];
}

// ---------------------------------------------------------------------------
// attention: one block per (b,h,q). S=256, d=64.
// ---------------------------------------------------------------------------
__global__ __launch_bounds__(256)
void attn_kernel(const float* __restrict__ qkv, float* __restrict__ o) {
    __shared__ float qs[64];
    __shared__ float P[256];
    __shared__ float red[8];
    int tid = threadIdx.x;
    int q = blockIdx.x & 255;
    int h = (blockIdx.x >> 8) % HEADS_;
    int b = blockIdx.x / (256*HEADS_);
    const float* qrow = qkv + ((size_t)(b*256 + q))*2304 + h*64;
    if (tid < 64) qs[tid] = qrow[tid];
    __syncthreads();
    const float* krow = qkv + ((size_t)(b*256 + tid))*2304 + 768 + h*64;
    float s = 0.0f;
    #pragma unroll 8
    for (int d = 0; d < 64; ++d) s += qs[d]*krow[d];
    s *= 0.125f;
    float m = s;
    #pragma unroll
    for (int off = 32; off; off >>= 1) m = fmaxf(m, __shfl_xor(m, off));
    if ((tid & 63) == 0) red[tid>>6] = m;
    __syncthreads();
    m = fmaxf(fmaxf(red[0],red[1]), fmaxf(red[2],red[3]));
    float p = expf(s - m);
    float sum = p;
    #pragma unroll
    for (int off = 32; off; off >>= 1) sum += __shfl_xor(sum, off);
    if ((tid & 63) == 0) red[4 + (tid>>6)] = sum;
    __syncthreads();
    sum = red[4]+red[5]+red[6]+red[7];
    P[tid] = p / sum;
    __syncthreads();
    int d = tid & 63, c = tid >> 6;
    const float* vb = qkv + ((size_t)(b*256))*2304 + 1536 + h*64 + d;
    float acc = 0.0f;
    #pragma unroll 4
    for (int kl = c*64; kl < c*64 + 64; ++kl) acc += P[kl] * vb[(size_t)kl*2304];
    __syncthreads();
    P[tid] = acc;
    __syncthreads();
    if (tid < 64) {
        float ov = P[tid] + P[tid+64] + P[tid+128] + P[tid+192];
        o[((size_t)(b*256 + q))*EMB_ + h*64 + tid] = ov;
    }
}

// ---------------------------------------------------------------------------
// head: roi bilinear-resize-mean (reduced to fixed weights) + fc + softmax
// ---------------------------------------------------------------------------
__global__ __launch_bounds__(256)
void head_kernel(const float* __restrict__ tok, const float* __restrict__ fcw,
                 const float* __restrict__ fcb, float* __restrict__ scores) {
    const int bx[6][4] = {{0,6,0,8},{4,11,0,8},{9,16,0,8},{0,6,8,16},{4,11,8,16},{9,16,8,16}};
    int box = blockIdx.x % 6, b = blockIdx.x / 6;
    int r0 = bx[box][0], r1 = bx[box][1], c0 = bx[box][2], c1 = bx[box][3];
    int rh = r1 - r0, rw = c1 - c0;
    __shared__ float wl[256];
    __shared__ float feats[768];
    __shared__ float red[4];
    int tid = threadIdx.x;
    int py = tid >> 4, px = tid & 15;
    float w = 0.0f;
    if (py >= r0 && py < r1 && px >= c0 && px < c1) {
        int ly = py - r0, lx = px - c0;
        float cy = 0.0f, cx = 0.0f;
        for (int o = 0; o < 16; ++o) {
            float sy = (o + 0.5f) * (float)rh * (1.0f/16.0f) - 0.5f;
            sy = fminf(fmaxf(sy, 0.0f), (float)(rh - 1));
            int i0 = (int)floorf(sy); float t = sy - (float)i0;
            if (ly == i0)     cy += 1.0f - t;
            if (ly == i0 + 1) cy += t;
            float sx = (o + 0.5f) * (float)rw * (1.0f/16.0f) - 0.5f;
            sx = fminf(fmaxf(sx, 0.0f), (float)(rw - 1));
            int j0 = (int)floorf(sx); float u = sx - (float)j0;
            if (lx == j0)     cx += 1.0f - u;
            if (lx == j0 + 1) cx += u;
        }
        w = (cy * (1.0f/16.0f)) * (cx * (1.0f/16.0f));
    }
    wl[tid] = w;
    __syncthreads();
    for (int e = tid; e < EMB_; e += 256) {
        float f = 0.0f;
        for (int iy = r0; iy < r1; ++iy)
            for (int ix = c0; ix < c1; ++ix) {
                int p = iy*16 + ix;
                f += wl[p] * tok[((size_t)(b*256 + p))*EMB_ + e];
            }
        feats[e] = f;
    }
    __syncthreads();
    float lg[4];
    #pragma unroll
    for (int cc = 0; cc < 4; ++cc) {
        float part = 0.0f;
        for (int e = tid; e < EMB_; e += 256) part += feats[e]*fcw[e*4 + cc];
        #pragma unroll
        for (int off = 32; off; off >>= 1) part += __shfl_xor(part, off);
        __syncthreads();
        if ((tid & 63) == 0) red[tid>>6] = part;
        __syncthreads();
        lg[cc] = red[0]+red[1]+red[2]+red[3] + fcb[cc];
    }
    if (tid == 0) {
        float mx = fmaxf(fmaxf(lg[0],lg[1]), fmaxf(lg[2],lg[3]));
        float e0 = expf(lg[0]-mx), e1 = expf(lg[1]-mx), e2 = expf(lg[2]-mx), e3 = expf(lg[3]-mx);
        float inv = 1.0f/(e0+e1+e2+e3);
        float* out = scores + (size_t)(b*6 + box)*4;
        out[0] = e0*inv; out[1] = e1*inv; out[2] = e2*inv; out[3] = e3*inv;
    }
}

// ===========================================================================
extern "C" void kernel_launch(void* const* d_in, const int* in_sizes, int n_in,
                              void* d_out, int out_size, void* d_ws, size_t ws_size,
                              hipStream_t stream) {
    (void)in_sizes; (void)n_in; (void)out_size; (void)ws_size;
    const float* x       = (const float*)d_in[0];
    const float* lm      = (const float*)d_in[1];
    const float* stn_w1  = (const float*)d_in[2];
    const float* stn_b1  = (const float*)d_in[3];
    const float* stn_w2  = (const float*)d_in[4];
    const float* stn_b2  = (const float*)d_in[5];
    const float* conv_w  = (const float*)d_in[6];
    const float* conv_b  = (const float*)d_in[7];
    const float* pe_w    = (const float*)d_in[8];
    const float* pe_b    = (const float*)d_in[9];
    const float* pos     = (const float*)d_in[10];
    const float* ln1_g   = (const float*)d_in[11];
    const float* ln1_b   = (const float*)d_in[12];
    const float* qkv_w   = (const float*)d_in[13];
    const float* qkv_b   = (const float*)d_in[14];
    const float* proj_w  = (const float*)d_in[15];
    const float* proj_b  = (const float*)d_in[16];
    const float* ln2_g   = (const float*)d_in[17];
    const float* ln2_b   = (const float*)d_in[18];
    const float* mlp_w1  = (const float*)d_in[19];
    const float* mlp_b1  = (const float*)d_in[20];
    const float* mlp_w2  = (const float*)d_in[21];
    const float* mlp_b2  = (const float*)d_in[22];
    const float* fc_w    = (const float*)d_in[23];
    const float* fc_b    = (const float*)d_in[24];

    float* out    = (float*)d_out;
    float* scores = out;                              // (B,6,4) = 384
    float* timg   = out + 384;                        // (B,3,512,512)
    float* tmask  = out + 384 + (size_t)B_*3*HH*WW;   // (B,1,512,512)

    float* ws = (float*)d_ws;
    size_t off = 0;
    auto take = [&](size_t n) { float* p = ws + off; off += (n + 63) & ~(size_t)63; return p; };
    float* slotBig = take(12582912);   // im2col A | qkv | mlp hidden
    float* slotA   = take(4194304);    // seg mask | conv feat | attn out
    float* tokb    = take((size_t)M_ * EMB_);
    float* tbuf    = take((size_t)M_ * EMB_);
    float* pooled  = take(16384);
    float* theta   = take(96);

    float* seg   = slotA;
    float* Aim   = slotBig;
    float* featC = slotA;
    float* qkvb  = slotBig;
    float* obuf  = slotA;
    float* hidd  = slotBig;

    // 1. zero seg mask, rasterize, pool, stn
    hipMemsetAsync(seg, 0, (size_t)B_*HH*WW*sizeof(float), stream);
    raster_kernel<<<B_, 128, 0, stream>>>(lm, seg);
    pool_kernel<<<64, 256, 0, stream>>>(seg, pooled);
    stn_kernel<<<B_, 64, 0, stream>>>(pooled, stn_w1, stn_b1, stn_w2, stn_b2, theta);

    // 2. fused affine grid + bilinear sample (img + mask) -> outputs
    gridsample_kernel<<<(B_*HH*WW)/256, 256, 0, stream>>>(x, seg, theta, timg, tmask);

    // 3. patchify conv as GEMM (with im2col), relu fused
    im2col_kernel<<<(M_*KCONV)/256, 256, 0, stream>>>(timg, Aim);
    gemm_kernel<EPI_RELU, true><<<dim3(NF_/64, M_/64), 256, 0, stream>>>(
        Aim, conv_w, conv_b, nullptr, featC, M_, NF_, KCONV);

    // 4. patch embed + pos
    gemm_kernel<EPI_POS, false><<<dim3(EMB_/64, M_/64), 256, 0, stream>>>(
        featC, pe_w, pe_b, pos, tokb, M_, EMB_, NF_);

    // 5. LN1 -> qkv
    ln_kernel<<<M_, 256, 0, stream>>>(tokb, ln1_g, ln1_b, tbuf);
    gemm_kernel<EPI_NONE, false><<<dim3((3*EMB_)/64, M_/64), 256, 0, stream>>>(
        tbuf, qkv_w, qkv_b, nullptr, qkvb, M_, 3*EMB_, EMB_);

    // 6. attention
    attn_kernel<<<B_*HEADS_*256, 256, 0, stream>>>(qkvb, obuf);

    // 7. proj + residual
    gemm_kernel<EPI_RESID, false><<<dim3(EMB_/64, M_/64), 256, 0, stream>>>(
        obuf, proj_w, proj_b, nullptr, tokb, M_, EMB_, EMB_);

    // 8. LN2 -> mlp
    ln_kernel<<<M_, 256, 0, stream>>>(tokb, ln2_g, ln2_b, tbuf);
    gemm_kernel<EPI_GELU, false><<<dim3((4*EMB_)/64, M_/64), 256, 0, stream>>>(
        tbuf, mlp_w1, mlp_b1, nullptr, hidd, M_, 4*EMB_, EMB_);
    gemm_kernel<EPI_RESID, false><<<dim3(EMB_/64, M_/64), 256, 0, stream>>>(
        hidd, mlp_w2, mlp_b2, nullptr, tokb, M_, EMB_, 4*EMB_);

    // 9. roi head + fc + softmax
    head_kernel<<<B_*6, 256, 0, stream>>>(tokb, fc_w, fc_b, scores);
}

// Round 2
// 685.536 us; speedup vs baseline: 2.9467x; 2.9467x over previous
//
#include <hip/hip_runtime.h>
#include <hip/hip_bf16.h>
#include <cstdint>

// ============================================================================
// Hybrid e2e STN pipeline, round 2: bf16 MFMA GEMMs + LDS-staged attention.
// ============================================================================

#define B_    16
#define HH    512
#define WW    512
#define NF_   1024
#define EMB_  768
#define HEADS_ 12
#define NTOK  256
#define M_    (B_*NTOK)      // 4096
#define KCONV 3072

typedef __bf16 bf16_t;
typedef __bf16 bf16x8 __attribute__((ext_vector_type(8)));
typedef float  f32x4  __attribute__((ext_vector_type(4)));

__device__ __forceinline__ float tanh_fast(float x) {
    return 1.0f - 2.0f / (__expf(2.0f * x) + 1.0f);
}

// ---------------------------------------------------------------------------
// rasterize (unchanged, verified)
// ---------------------------------------------------------------------------
__global__ __launch_bounds__(128)
void raster_kernel(const float* __restrict__ lm, float* __restrict__ seg) {
    int b = blockIdx.x;
    int s = threadIdx.x;
    if (s >= 117) return;
    int seg0 = (s < 43) ? s : ((s < 92) ? s + 1 : s + 2);
    const float* p = lm + (size_t)b * 240;
    int p1x = min(max((int)(p[seg0*2 + 0] * 512.0f), 0), 511);
    int p1y = min(max((int)(p[seg0*2 + 1] * 512.0f), 0), 511);
    int p2x = min(max((int)(p[(seg0+1)*2 + 0] * 512.0f), 0), 511);
    int p2y = min(max((int)(p[(seg0+1)*2 + 1] * 512.0f), 0), 511);
    int dy = p2y - p1y, dx = p2x - p1x;
    int kmax = min(dy, dx);
    float* sb = seg + (size_t)b * (HH*WW);
    for (int k = 0; k < kmax; ++k) {
        int yi = min(p1y + k, 511);
        int xi = min(p1x + k, 511);
        sb[yi*WW + xi] = 1.0f;
    }
}

// ---------------------------------------------------------------------------
// pool + stn (unchanged, verified)
// ---------------------------------------------------------------------------
__global__ __launch_bounds__(256)
void pool_kernel(const float* __restrict__ seg, float* __restrict__ pooled) {
    int idx = blockIdx.x * 256 + threadIdx.x;
    int ox = idx & 31, oy = (idx >> 5) & 31, b = idx >> 10;
    const float* sb = seg + (size_t)b * (HH*WW) + (oy*16)*WW + ox*16;
    float s = 0.0f;
    for (int dy = 0; dy < 16; ++dy) {
        #pragma unroll
        for (int dx = 0; dx < 16; ++dx) s += sb[dy*WW + dx];
    }
    pooled[idx] = s * (1.0f/256.0f);
}

__global__ __launch_bounds__(64)
void stn_kernel(const float* __restrict__ pooled,
                const float* __restrict__ w1, const float* __restrict__ b1,
                const float* __restrict__ w2, const float* __restrict__ b2,
                float* __restrict__ theta) {
    __shared__ float pl[1024];
    __shared__ float hl[50];
    int b = blockIdx.x, tid = threadIdx.x;
    for (int i = tid; i < 1024; i += 64) pl[i] = pooled[b*1024 + i];
    __syncthreads();
    if (tid < 50) {
        float acc = b1[tid];
        for (int k = 0; k < 1024; ++k) acc += pl[k] * w1[k*50 + tid];
        hl[tid] = tanhf(acc);
    }
    __syncthreads();
    if (tid < 6) {
        float acc = b2[tid];
        for (int k = 0; k < 50; ++k) acc += hl[k] * w2[k*6 + tid];
        theta[b*6 + tid] = acc;
    }
}

// ---------------------------------------------------------------------------
// fused affine_grid + grid_sample (unchanged, verified)
// ---------------------------------------------------------------------------
__global__ __launch_bounds__(256)
void gridsample_kernel(const float* __restrict__ x, const float* __restrict__ seg,
                       const float* __restrict__ theta,
                       float* __restrict__ timg, float* __restrict__ tmask) {
    size_t idx = (size_t)blockIdx.x * 256 + threadIdx.x;
    int xx = (int)(idx & 511);
    int yy = (int)((idx >> 9) & 511);
    int b  = (int)(idx >> 18);
    __shared__ float th[6];
    if (threadIdx.x < 6) th[threadIdx.x] = theta[b*6 + threadIdx.x];
    __syncthreads();
    float gx = (2.0f*xx + 1.0f) * (1.0f/512.0f) - 1.0f;
    float gy = (2.0f*yy + 1.0f) * (1.0f/512.0f) - 1.0f;
    float g0 = gx*th[0] + gy*th[1] + th[2];
    float g1 = gx*th[3] + gy*th[4] + th[5];
    float fx = ((g0 + 1.0f)*512.0f - 1.0f)*0.5f;
    float fy = ((g1 + 1.0f)*512.0f - 1.0f)*0.5f;
    float x0f = floorf(fx), y0f = floorf(fy);
    float wx1 = fx - x0f,  wy1 = fy - y0f;
    int ix0 = (int)x0f, iy0 = (int)y0f;
    int ix1 = ix0 + 1,  iy1 = iy0 + 1;
    float fy0ok = (iy0 >= 0 && iy0 < HH) ? 1.0f : 0.0f;
    float fy1ok = (iy1 >= 0 && iy1 < HH) ? 1.0f : 0.0f;
    float fx0ok = (ix0 >= 0 && ix0 < WW) ? 1.0f : 0.0f;
    float fx1ok = (ix1 >= 0 && ix1 < WW) ? 1.0f : 0.0f;
    float w00 = (1.0f-wy1)*(1.0f-wx1) * fy0ok * fx0ok;
    float w01 = (1.0f-wy1)*wx1        * fy0ok * fx1ok;
    float w10 = wy1*(1.0f-wx1)        * fy1ok * fx0ok;
    float w11 = wy1*wx1               * fy1ok * fx1ok;
    int cx0 = min(max(ix0,0),511), cx1 = min(max(ix1,0),511);
    int cy0 = min(max(iy0,0),511), cy1 = min(max(iy1,0),511);
    int i00 = cy0*WW + cx0, i01 = cy0*WW + cx1, i10 = cy1*WW + cx0, i11 = cy1*WW + cx1;
    size_t pix = (size_t)yy*WW + xx;
    #pragma unroll
    for (int c = 0; c < 3; ++c) {
        const float* pl = x + ((size_t)(b*3 + c)) * (HH*WW);
        float v = w00*pl[i00] + w01*pl[i01] + w10*pl[i10] + w11*pl[i11];
        timg[((size_t)(b*3 + c))*(HH*WW) + pix] = v;
    }
    const float* sp = seg + (size_t)b * (HH*WW);
    float mv = w00*sp[i00] + w01*sp[i01] + w10*sp[i10] + w11*sp[i11];
    tmask[(size_t)b*(HH*WW) + pix] = mv;
}

// ---------------------------------------------------------------------------
// conversions: fp32 -> bf16 (linear), fp32 [K][N] -> bf16 [N][K] (transpose)
// ---------------------------------------------------------------------------
__global__ __launch_bounds__(256)
void convert_bf16_kernel(const float* __restrict__ in, bf16_t* __restrict__ out) {
    int idx = (blockIdx.x * 256 + threadIdx.x) * 8;
    float4 v0 = *reinterpret_cast<const float4*>(in + idx);
    float4 v1 = *reinterpret_cast<const float4*>(in + idx + 4);
    bf16x8 o;
    o[0]=(bf16_t)v0.x; o[1]=(bf16_t)v0.y; o[2]=(bf16_t)v0.z; o[3]=(bf16_t)v0.w;
    o[4]=(bf16_t)v1.x; o[5]=(bf16_t)v1.y; o[6]=(bf16_t)v1.z; o[7]=(bf16_t)v1.w;
    *reinterpret_cast<bf16x8*>(out + idx) = o;
}

__global__ __launch_bounds__(256)
void transpose_bf16_kernel(const float* __restrict__ in, bf16_t* __restrict__ out,
                           int K, int N) {   // in[K][N] -> out[N][K]
    __shared__ float tile[32][33];
    int bk = blockIdx.y * 32, bn = blockIdx.x * 32;
    int r = threadIdx.x >> 5, c = threadIdx.x & 31;
    #pragma unroll
    for (int i = 0; i < 4; ++i)
        tile[r + 8*i][c] = in[(size_t)(bk + r + 8*i) * N + bn + c];
    __syncthreads();
    #pragma unroll
    for (int i = 0; i < 4; ++i)
        out[(size_t)(bn + r + 8*i) * K + bk + c] = (bf16_t)tile[c][r + 8*i];
}

// ---------------------------------------------------------------------------
// im2col -> bf16; 8 elements per thread (contiguous along kx)
// ---------------------------------------------------------------------------
__global__ __launch_bounds__(256)
void im2col_bf16_kernel(const float* __restrict__ timg, bf16_t* __restrict__ A) {
    int t = (blockIdx.x * 256 + threadIdx.x) * 8;   // over M_*KCONV
    int k = t % KCONV;
    int m = t / KCONV;
    int kx = k & 31, ky = (k >> 5) & 31, c = k >> 10;
    int px = m & 15, py = (m >> 4) & 15, b = m >> 8;
    const float* src = timg + ((size_t)(b*3 + c)*HH + py*32 + ky)*WW + px*32 + kx;
    float4 v0 = *reinterpret_cast<const float4*>(src);
    float4 v1 = *reinterpret_cast<const float4*>(src + 4);
    bf16x8 o;
    o[0]=(bf16_t)v0.x; o[1]=(bf16_t)v0.y; o[2]=(bf16_t)v0.z; o[3]=(bf16_t)v0.w;
    o[4]=(bf16_t)v1.x; o[5]=(bf16_t)v1.y; o[6]=(bf16_t)v1.z; o[7]=(bf16_t)v1.w;
    *reinterpret_cast<bf16x8*>(A + t) = o;
}

// ---------------------------------------------------------------------------
// bf16 MFMA GEMM: C = A(MxK,bf16) * Bt(NxK,bf16)^T, fp32 accum.
// 128x128 tile, BK=32, 256 thr = 4 waves, each wave 64x64 (4x4 frags 16x16).
// LDS: [row][k] bf16, 64B rows, 16B slots XOR-swizzled by (row>>1)&3.
// Frag layouts (mfma_f32_16x16x32_bf16):
//   A: lane l holds A[l&15][(l>>4)*8 + j]   B: lane l holds B[(l>>4)*8+j][l&15]
//   D: lane l reg r -> D[(l>>4)*4 + r][l&15]   [measured: learn_hip m89]
// ---------------------------------------------------------------------------
enum { EPI_CONV=0, EPI_PE=1, EPI_QKV=2, EPI_PROJ=3, EPI_GELU=4, EPI_MLP2=5 };

template<int EPI>
__global__ __launch_bounds__(256)
void gemm_bf16_kernel(const bf16_t* __restrict__ A, const bf16_t* __restrict__ Bt,
                      const float* __restrict__ bias, const float* __restrict__ extra,
                      float* __restrict__ Cf, bf16_t* __restrict__ Cb,
                      int M, int N, int K) {
    __shared__ bf16_t As[128*32];
    __shared__ bf16_t Bs[128*32];
    const int tid  = threadIdx.x;
    const int bm   = blockIdx.y * 128;
    const int bn   = blockIdx.x * 128;
    const int lane = tid & 63;
    const int w    = tid >> 6;
    const int wm   = (w & 1) * 64;
    const int wn   = (w >> 1) * 64;
    const int rr   = lane & 15;
    const int g    = lane >> 4;

    f32x4 acc[4][4] = {};

    const int m0a = tid >> 2,          ksa = tid & 3;          // idx 0..255
    const int m0b = (tid + 256) >> 2,  ksb = tid & 3;          // idx 256..511
    const int sla = ksa ^ ((m0a >> 1) & 3);
    const int slb = ksb ^ ((m0b >> 1) & 3);

    for (int k0 = 0; k0 < K; k0 += 32) {
        // stage A tile (128 rows x 32 k)
        bf16x8 va0 = *reinterpret_cast<const bf16x8*>(A + (size_t)(bm + m0a)*K + k0 + ksa*8);
        bf16x8 va1 = *reinterpret_cast<const bf16x8*>(A + (size_t)(bm + m0b)*K + k0 + ksb*8);
        bf16x8 vb0 = *reinterpret_cast<const bf16x8*>(Bt + (size_t)(bn + m0a)*K + k0 + ksa*8);
        bf16x8 vb1 = *reinterpret_cast<const bf16x8*>(Bt + (size_t)(bn + m0b)*K + k0 + ksb*8);
        *reinterpret_cast<bf16x8*>(As + m0a*32 + sla*8) = va0;
        *reinterpret_cast<bf16x8*>(As + m0b*32 + slb*8) = va1;
        *reinterpret_cast<bf16x8*>(Bs + m0a*32 + sla*8) = vb0;
        *reinterpret_cast<bf16x8*>(Bs + m0b*32 + slb*8) = vb1;
        __syncthreads();

        bf16x8 af[4], bf[4];
        #pragma unroll
        for (int i = 0; i < 4; ++i) {
            int mr = wm + i*16 + rr;
            af[i] = *reinterpret_cast<const bf16x8*>(As + mr*32 + (g ^ ((mr >> 1) & 3))*8);
            int nr = wn + i*16 + rr;
            bf[i] = *reinterpret_cast<const bf16x8*>(Bs + nr*32 + (g ^ ((nr >> 1) & 3))*8);
        }
        #pragma unroll
        for (int i = 0; i < 4; ++i)
            #pragma unroll
            for (int j = 0; j < 4; ++j)
                acc[i][j] = __builtin_amdgcn_mfma_f32_16x16x32_bf16(af[i], bf[j], acc[i][j], 0, 0, 0);
        __syncthreads();
    }

    // epilogue
    #pragma unroll
    for (int i = 0; i < 4; ++i) {
        #pragma unroll
        for (int j = 0; j < 4; ++j) {
            #pragma unroll
            for (int r = 0; r < 4; ++r) {
                int m = bm + wm + i*16 + g*4 + r;
                int n = bn + wn + j*16 + rr;
                size_t o = (size_t)m * N + n;
                float v = acc[i][j][r] + bias[n];
                if (EPI == EPI_CONV) {
                    Cb[o] = (bf16_t)fmaxf(v, 0.0f);
                } else if (EPI == EPI_PE) {
                    Cf[o] = v + extra[(size_t)(m & 255)*N + n];
                } else if (EPI == EPI_QKV) {
                    Cb[o] = (bf16_t)v;
                } else if (EPI == EPI_PROJ || EPI == EPI_MLP2) {
                    Cf[o] = v + Cf[o];
                } else if (EPI == EPI_GELU) {
                    float u = v;
                    float gl = 0.5f*u*(1.0f + tanh_fast(0.7978845608028654f*(u + 0.044715f*u*u*u)));
                    Cb[o] = (bf16_t)gl;
                }
            }
        }
    }
}

// ---------------------------------------------------------------------------
// layernorm rows of 768, fp32 in -> bf16 out
// ---------------------------------------------------------------------------
__global__ __launch_bounds__(256)
void ln_kernel(const float* __restrict__ x, const float* __restrict__ g,
               const float* __restrict__ be, bf16_t* __restrict__ out) {
    int r = blockIdx.x, tid = threadIdx.x;
    const float* xr = x + (size_t)r * EMB_;
    float v0 = xr[tid], v1 = xr[tid+256], v2 = xr[tid+512];
    float s = v0+v1+v2, s2 = v0*v0 + v1*v1 + v2*v2;
    __shared__ float red[8];
    #pragma unroll
    for (int off = 32; off; off >>= 1) { s += __shfl_xor(s, off); s2 += __shfl_xor(s2, off); }
    if ((tid & 63) == 0) { red[tid>>6] = s; red[4 + (tid>>6)] = s2; }
    __syncthreads();
    s  = red[0]+red[1]+red[2]+red[3];
    s2 = red[4]+red[5]+red[6]+red[7];
    float mean = s * (1.0f/768.0f);
    float var  = s2 * (1.0f/768.0f) - mean*mean;
    float rstd = rsqrtf(var + 1e-5f);
    bf16_t* orow = out + (size_t)r * EMB_;
    orow[tid]     = (bf16_t)((v0-mean)*rstd*g[tid]     + be[tid]);
    orow[tid+256] = (bf16_t)((v1-mean)*rstd*g[tid+256] + be[tid+256]);
    orow[tid+512] = (bf16_t)((v2-mean)*rstd*g[tid+512] + be[tid+512]);
}

// ---------------------------------------------------------------------------
// attention: one block per (b,h); K,V staged in LDS fp32; thread t owns q=t.
// Two-pass softmax (max, then exp+PV).
// ---------------------------------------------------------------------------
__global__ __launch_bounds__(256)
void attn_kernel2(const bf16_t* __restrict__ qkv, bf16_t* __restrict__ o) {
    __shared__ float Ks[256][68];
    __shared__ float Vs[256][68];
    int tid = threadIdx.x;
    int h = blockIdx.x % HEADS_;
    int b = blockIdx.x / HEADS_;
    const bf16_t* base = qkv + (size_t)(b * 256) * 2304;

    // stage K,V row tid
    {
        const bf16_t* kr = base + (size_t)tid * 2304 + 768  + h*64;
        const bf16_t* vr = base + (size_t)tid * 2304 + 1536 + h*64;
        #pragma unroll
        for (int d = 0; d < 64; d += 8) {
            bf16x8 kv = *reinterpret_cast<const bf16x8*>(kr + d);
            bf16x8 vv = *reinterpret_cast<const bf16x8*>(vr + d);
            float4 klo = { (float)kv[0], (float)kv[1], (float)kv[2], (float)kv[3] };
            float4 khi = { (float)kv[4], (float)kv[5], (float)kv[6], (float)kv[7] };
            float4 vlo = { (float)vv[0], (float)vv[1], (float)vv[2], (float)vv[3] };
            float4 vhi = { (float)vv[4], (float)vv[5], (float)vv[6], (float)vv[7] };
            *reinterpret_cast<float4*>(&Ks[tid][d])   = klo;
            *reinterpret_cast<float4*>(&Ks[tid][d+4]) = khi;
            *reinterpret_cast<float4*>(&Vs[tid][d])   = vlo;
            *reinterpret_cast<float4*>(&Vs[tid][d+4]) = vhi;
        }
    }
    // q row into registers
    float q[64];
    {
        const bf16_t* qr = base + (size_t)tid * 2304 + h*64;
        #pragma unroll
        for (int d = 0; d < 64; d += 8) {
            bf16x8 qv = *reinterpret_cast<const bf16x8*>(qr + d);
            #pragma unroll
            for (int j = 0; j < 8; ++j) q[d + j] = (float)qv[j];
        }
    }
    __syncthreads();

    // pass 1: row max
    float mx = -3.0e38f;
    for (int k = 0; k < 256; ++k) {
        const float* kr = &Ks[k][0];
        float s0=0.f, s1=0.f, s2=0.f, s3=0.f;
        #pragma unroll
        for (int d = 0; d < 64; d += 4) {
            s0 = fmaf(q[d+0], kr[d+0], s0);
            s1 = fmaf(q[d+1], kr[d+1], s1);
            s2 = fmaf(q[d+2], kr[d+2], s2);
            s3 = fmaf(q[d+3], kr[d+3], s3);
        }
        mx = fmaxf(mx, (s0+s1)+(s2+s3));
    }
    // pass 2: exp + PV
    float l = 0.0f;
    float o_[64];
    #pragma unroll
    for (int d = 0; d < 64; ++d) o_[d] = 0.0f;
    for (int k = 0; k < 256; ++k) {
        const float* kr = &Ks[k][0];
        float s0=0.f, s1=0.f, s2=0.f, s3=0.f;
        #pragma unroll
        for (int d = 0; d < 64; d += 4) {
            s0 = fmaf(q[d+0], kr[d+0], s0);
            s1 = fmaf(q[d+1], kr[d+1], s1);
            s2 = fmaf(q[d+2], kr[d+2], s2);
            s3 = fmaf(q[d+3], kr[d+3], s3);
        }
        float s = (s0+s1)+(s2+s3);
        float p = __expf((s - mx) * 0.125f);
        l += p;
        const float* vr = &Vs[k][0];
        #pragma unroll
        for (int d = 0; d < 64; ++d) o_[d] = fmaf(p, vr[d], o_[d]);
    }
    float inv = 1.0f / l;
    bf16_t* orow = o + (size_t)(b*256 + tid)*EMB_ + h*64;
    #pragma unroll
    for (int d = 0; d < 64; d += 8) {
        bf16x8 ov;
        #pragma unroll
        for (int j = 0; j < 8; ++j) ov[j] = (bf16_t)(o_[d+j] * inv);
        *reinterpret_cast<bf16x8*>(orow + d) = ov;
    }
}

// ---------------------------------------------------------------------------
// head: roi resize-mean as fixed weights + fc + softmax (reads fp32 tok)
// ---------------------------------------------------------------------------
__global__ __launch_bounds__(256)
void head_kernel(const float* __restrict__ tok, const float* __restrict__ fcw,
                 const float* __restrict__ fcb, float* __restrict__ scores) {
    const int bx[6][4] = {{0,6,0,8},{4,11,0,8},{9,16,0,8},{0,6,8,16},{4,11,8,16},{9,16,8,16}};
    int box = blockIdx.x % 6, b = blockIdx.x / 6;
    int r0 = bx[box][0], r1 = bx[box][1], c0 = bx[box][2], c1 = bx[box][3];
    int rh = r1 - r0, rw = c1 - c0;
    __shared__ float wl[256];
    __shared__ float feats[768];
    __shared__ float red[4];
    int tid = threadIdx.x;
    int py = tid >> 4, px = tid & 15;
    float w = 0.0f;
    if (py >= r0 && py < r1 && px >= c0 && px < c1) {
        int ly = py - r0, lx = px - c0;
        float cy = 0.0f, cx = 0.0f;
        for (int o = 0; o < 16; ++o) {
            float sy = (o + 0.5f) * (float)rh * (1.0f/16.0f) - 0.5f;
            sy = fminf(fmaxf(sy, 0.0f), (float)(rh - 1));
            int i0 = (int)floorf(sy); float t = sy - (float)i0;
            if (ly == i0)     cy += 1.0f - t;
            if (ly == i0 + 1) cy += t;
            float sx = (o + 0.5f) * (float)rw * (1.0f/16.0f) - 0.5f;
            sx = fminf(fmaxf(sx, 0.0f), (float)(rw - 1));
            int j0 = (int)floorf(sx); float u = sx - (float)j0;
            if (lx == j0)     cx += 1.0f - u;
            if (lx == j0 + 1) cx += u;
        }
        w = (cy * (1.0f/16.0f)) * (cx * (1.0f/16.0f));
    }
    wl[tid] = w;
    __syncthreads();
    for (int e = tid; e < EMB_; e += 256) {
        float f = 0.0f;
        for (int iy = r0; iy < r1; ++iy)
            for (int ix = c0; ix < c1; ++ix) {
                int p = iy*16 + ix;
                f += wl[p] * tok[((size_t)(b*256 + p))*EMB_ + e];
            }
        feats[e] = f;
    }
    __syncthreads();
    float lg[4];
    #pragma unroll
    for (int cc = 0; cc < 4; ++cc) {
        float part = 0.0f;
        for (int e = tid; e < EMB_; e += 256) part += feats[e]*fcw[e*4 + cc];
        #pragma unroll
        for (int off = 32; off; off >>= 1) part += __shfl_xor(part, off);
        __syncthreads();
        if ((tid & 63) == 0) red[tid>>6] = part;
        __syncthreads();
        lg[cc] = red[0]+red[1]+red[2]+red[3] + fcb[cc];
    }
    if (tid == 0) {
        float mx = fmaxf(fmaxf(lg[0],lg[1]), fmaxf(lg[2],lg[3]));
        float e0 = expf(lg[0]-mx), e1 = expf(lg[1]-mx), e2 = expf(lg[2]-mx), e3 = expf(lg[3]-mx);
        float inv = 1.0f/(e0+e1+e2+e3);
        float* out = scores + (size_t)(b*6 + box)*4;
        out[0] = e0*inv; out[1] = e1*inv; out[2] = e2*inv; out[3] = e3*inv;
    }
}

// ===========================================================================
extern "C" void kernel_launch(void* const* d_in, const int* in_sizes, int n_in,
                              void* d_out, int out_size, void* d_ws, size_t ws_size,
                              hipStream_t stream) {
    (void)in_sizes; (void)n_in; (void)out_size; (void)ws_size;
    const float* x       = (const float*)d_in[0];
    const float* lm      = (const float*)d_in[1];
    const float* stn_w1  = (const float*)d_in[2];
    const float* stn_b1  = (const float*)d_in[3];
    const float* stn_w2  = (const float*)d_in[4];
    const float* stn_b2  = (const float*)d_in[5];
    const float* conv_w  = (const float*)d_in[6];
    const float* conv_b  = (const float*)d_in[7];
    const float* pe_w    = (const float*)d_in[8];
    const float* pe_b    = (const float*)d_in[9];
    const float* pos     = (const float*)d_in[10];
    const float* ln1_g   = (const float*)d_in[11];
    const float* ln1_b   = (const float*)d_in[12];
    const float* qkv_w   = (const float*)d_in[13];
    const float* qkv_b   = (const float*)d_in[14];
    const float* proj_w  = (const float*)d_in[15];
    const float* proj_b  = (const float*)d_in[16];
    const float* ln2_g   = (const float*)d_in[17];
    const float* ln2_b   = (const float*)d_in[18];
    const float* mlp_w1  = (const float*)d_in[19];
    const float* mlp_b1  = (const float*)d_in[20];
    const float* mlp_w2  = (const float*)d_in[21];
    const float* mlp_b2  = (const float*)d_in[22];
    const float* fc_w    = (const float*)d_in[23];
    const float* fc_b    = (const float*)d_in[24];

    float* out    = (float*)d_out;
    float* scores = out;
    float* timg   = out + 384;
    float* tmask  = out + 384 + (size_t)B_*3*HH*WW;

    char* ws = (char*)d_ws;
    size_t off = 0;
    auto alloc = [&](size_t bytes) {
        off = (off + 255) & ~(size_t)255;
        void* p = ws + off; off += bytes; return p;
    };
    // slotBig: seg(fp32,16MB) -> Aim(bf16,24MB) -> hidden(bf16,24MB)
    char*   slotBig = (char*)alloc(25165824);
    bf16_t* qkvb    = (bf16_t*)alloc((size_t)M_*2304*2);
    // slotC: featC(bf16,8MB) -> obuf(bf16,6MB)
    char*   slotC   = (char*)alloc((size_t)M_*NF_*2);
    float*  tok     = (float*)alloc((size_t)M_*EMB_*4);
    bf16_t* tbuf    = (bf16_t*)alloc((size_t)M_*EMB_*2);
    bf16_t* conv_wb = (bf16_t*)alloc((size_t)NF_*KCONV*2);
    bf16_t* pe_wb   = (bf16_t*)alloc((size_t)EMB_*NF_*2);
    bf16_t* qkv_wb  = (bf16_t*)alloc((size_t)3*EMB_*EMB_*2);
    bf16_t* proj_wb = (bf16_t*)alloc((size_t)EMB_*EMB_*2);
    bf16_t* mlp1_wb = (bf16_t*)alloc((size_t)4*EMB_*EMB_*2);
    bf16_t* mlp2_wb = (bf16_t*)alloc((size_t)EMB_*4*EMB_*2);
    float*  pooled  = (float*)alloc(16384*4);
    float*  theta   = (float*)alloc(96*4);

    float*  seg    = (float*)slotBig;
    bf16_t* Aim    = (bf16_t*)slotBig;
    bf16_t* hidden = (bf16_t*)slotBig;
    bf16_t* featC  = (bf16_t*)slotC;
    bf16_t* obuf   = (bf16_t*)slotC;

    // weight conversions (independent)
    convert_bf16_kernel<<<(NF_*KCONV)/8/256, 256, 0, stream>>>(conv_w, conv_wb);
    transpose_bf16_kernel<<<dim3(EMB_/32, NF_/32),    256, 0, stream>>>(pe_w,   pe_wb,   NF_,  EMB_);
    transpose_bf16_kernel<<<dim3(3*EMB_/32, EMB_/32), 256, 0, stream>>>(qkv_w,  qkv_wb,  EMB_, 3*EMB_);
    transpose_bf16_kernel<<<dim3(EMB_/32, EMB_/32),   256, 0, stream>>>(proj_w, proj_wb, EMB_, EMB_);
    transpose_bf16_kernel<<<dim3(4*EMB_/32, EMB_/32), 256, 0, stream>>>(mlp_w1, mlp1_wb, EMB_, 4*EMB_);
    transpose_bf16_kernel<<<dim3(EMB_/32, 4*EMB_/32), 256, 0, stream>>>(mlp_w2, mlp2_wb, 4*EMB_, EMB_);

    // mask path
    hipMemsetAsync(seg, 0, (size_t)B_*HH*WW*sizeof(float), stream);
    raster_kernel<<<B_, 128, 0, stream>>>(lm, seg);
    pool_kernel<<<64, 256, 0, stream>>>(seg, pooled);
    stn_kernel<<<B_, 64, 0, stream>>>(pooled, stn_w1, stn_b1, stn_w2, stn_b2, theta);
    gridsample_kernel<<<(B_*HH*WW)/256, 256, 0, stream>>>(x, seg, theta, timg, tmask);

    // conv as GEMM
    im2col_bf16_kernel<<<(M_*KCONV)/8/256, 256, 0, stream>>>(timg, Aim);
    gemm_bf16_kernel<EPI_CONV><<<dim3(NF_/128, M_/128), 256, 0, stream>>>(
        Aim, conv_wb, conv_b, nullptr, nullptr, featC, M_, NF_, KCONV);

    // patch embed + pos -> tok (fp32 residual stream)
    gemm_bf16_kernel<EPI_PE><<<dim3(EMB_/128, M_/128), 256, 0, stream>>>(
        featC, pe_wb, pe_b, pos, tok, nullptr, M_, EMB_, NF_);

    // LN1 -> qkv
    ln_kernel<<<M_, 256, 0, stream>>>(tok, ln1_g, ln1_b, tbuf);
    gemm_bf16_kernel<EPI_QKV><<<dim3(3*EMB_/128, M_/128), 256, 0, stream>>>(
        tbuf, qkv_wb, qkv_b, nullptr, nullptr, qkvb, M_, 3*EMB_, EMB_);

    // attention
    attn_kernel2<<<B_*HEADS_, 256, 0, stream>>>(qkvb, obuf);

    // proj + residual
    gemm_bf16_kernel<EPI_PROJ><<<dim3(EMB_/128, M_/128), 256, 0, stream>>>(
        obuf, proj_wb, proj_b, nullptr, tok, nullptr, M_, EMB_, EMB_);

    // LN2 -> mlp
    ln_kernel<<<M_, 256, 0, stream>>>(tok, ln2_g, ln2_b, tbuf);
    gemm_bf16_kernel<EPI_GELU><<<dim3(4*EMB_/128, M_/128), 256, 0, stream>>>(
        tbuf, mlp1_wb, mlp_b1, nullptr, nullptr, hidden, M_, 4*EMB_, EMB_);
    gemm_bf16_kernel<EPI_MLP2><<<dim3(EMB_/128, M_/128), 256, 0, stream>>>(
        hidden, mlp2_wb, mlp_b2, nullptr, tok, nullptr, M_, EMB_, 4*EMB_);

    // head
    head_kernel<<<B_*6, 256, 0, stream>>>(tok, fc_w, fc_b, scores);
}